// Round 15
// baseline (410.865 us; speedup 1.0000x reference)
//
#include <hip/hip_runtime.h>
#include <hip/hip_bf16.h>
#include <hip/hip_cooperative_groups.h>

namespace cg = cooperative_groups;

typedef unsigned short u16;
typedef __attribute__((ext_vector_type(8))) short bf16x8;
typedef __attribute__((ext_vector_type(4))) float f32x4;

#define DEVINL __device__ __forceinline__

struct alignas(16) U8 { u16 v[8]; };

DEVINL u16 f2bf(float f) {
    unsigned int x = __float_as_uint(f);
    unsigned int r = (x + 0x7fffu + ((x >> 16) & 1u)) >> 16;
    return (u16)r;
}

DEVINL void gload_lds16(const void* g, void* l) {
    __builtin_amdgcn_global_load_lds(
        (const __attribute__((address_space(1))) void*)g,
        (__attribute__((address_space(3))) void*)l,
        16, 0, 0);
}

// ---------------------------------------------------------------------------
// staging helpers with hoisted addressing
// ---------------------------------------------------------------------------
DEVINL void stA(const u16* p, int uni, int lo, int ld, u16* dst, int w) {
    gload_lds16(p + uni + lo, dst + ((w << 3) << 6));
    gload_lds16(p + uni + lo + (ld << 7), dst + ((128 + (w << 3)) << 6));
}
DEVINL void stB(const u16* p, int uni, int lo, int ld, u16* dst, int w) {
    int d0 = ((w >> 2) << 6) + ((w & 3) << 3);
    gload_lds16(p + uni + lo, dst + (d0 << 6));
    gload_lds16(p + uni + lo + (ld << 7), dst + ((128 + d0) << 6));
}

// segment info for concatenated K (tiles 0-15: x/W_in, 16-47: h/W_hh)
struct SegU { const u16* pA; const u16* pB; int uA; int uB; int ld; int loA; int loB; };

DEVINL SegU segu(int kt, const u16* X, const u16* W1, const u16* H, const u16* W2,
                 int rbA, int rbB, int loA1, int loA2, int loB1, int loB2) {
    SegU s;
    if (kt < 16) {
        int k0 = kt << 6;
        s.pA = X; s.pB = W1; s.ld = 1024;
        s.uA = (rbA << 10) + k0; s.uB = (rbB << 10) + k0;
        s.loA = loA1; s.loB = loB1;
    } else {
        int k0 = (kt - 16) << 6;
        s.pA = H; s.pB = W2; s.ld = 2048;
        s.uA = (rbA << 11) + k0; s.uB = (rbB << 11) + k0;
        s.loA = loA2; s.loB = loB2;
    }
    return s;
}

#define STA(S, SET, BUF) stA((S).pA, (S).uA + ((SET) ? ((S).ld << 6) : 0), (S).loA, \
                             (S).ld, Alds + (BUF) * 16384 + (SET) * 4096, w)
#define STB(S, SET, BUF) stB((S).pB, (S).uB + ((SET) ? ((S).ld << 5) : 0), (S).loB, \
                             (S).ld, Blds + (BUF) * 16384 + (SET) * 2048, w)

#define RD_A(MQ, BUF) do { \
    _Pragma("unroll") for (int i = 0; i < 4; ++i) { \
        afr[i][0] = *(const bf16x8*)(fA0 + (BUF) * 32768 + (MQ) * 8192 + i * 2048); \
        afr[i][1] = *(const bf16x8*)(fA1 + (BUF) * 32768 + (MQ) * 8192 + i * 2048); \
    } } while (0)

#define RD_B_ALL(BUF) do { \
    _Pragma("unroll") for (int n = 0; n < 4; ++n) { \
        bfr[n][0] = *(const bf16x8*)(fB0 + (BUF) * 32768 + n * 2048); \
        bfr[n][1] = *(const bf16x8*)(fB1 + (BUF) * 32768 + n * 2048); \
    } } while (0)

#define MFMA_M(MQ) do { \
    _Pragma("unroll") for (int i = 0; i < 4; ++i) \
    _Pragma("unroll") for (int n = 0; n < 4; ++n) \
    _Pragma("unroll") for (int kk = 0; kk < 2; ++kk) \
        acc[(MQ)*4+i][n] = __builtin_amdgcn_mfma_f32_16x16x32_bf16( \
            afr[i][kk], bfr[n][kk], acc[(MQ)*4+i][n], 0, 0, 0); \
    } while (0)

#define PHASE_MID() __builtin_amdgcn_s_setprio(1)

#define BAREND() do { \
    __builtin_amdgcn_s_setprio(0); \
    asm volatile("s_waitcnt lgkmcnt(0)" ::: "memory"); \
    asm volatile("s_barrier" ::: "memory"); \
    } while (0)

#define BAREND_VM() do { \
    __builtin_amdgcn_s_setprio(0); \
    asm volatile("s_waitcnt vmcnt(4) lgkmcnt(0)" ::: "memory"); \
    asm volatile("s_barrier" ::: "memory"); \
    } while (0)

#define BAREND_VM3() do { \
    __builtin_amdgcn_s_setprio(0); \
    asm volatile("s_waitcnt vmcnt(3) lgkmcnt(0)" ::: "memory"); \
    asm volatile("s_barrier" ::: "memory"); \
    } while (0)

// gemm3 macros
#define G3_STA(KT, SET, BUF) do { \
    int uni_ = uA3 + ((KT) << 6) + ((SET) ? (2048 << 6) : 0); \
    u16* dst_ = g3A + (BUF) * 16384 + (SET) * 4096; \
    gload_lds16(hn_bf + uni_ + lo3, dst_ + ((w << 3) << 6)); \
    gload_lds16(hn_bf + uni_ + lo3 + (2048 << 7), dst_ + ((128 + (w << 3)) << 6)); \
    } while (0)

#define G3_STB(KT, SET, BUF) do { \
    int uni_ = uB3 + ((KT) << 6) + ((SET) ? (2048 << 6) : 0); \
    gload_lds16(wout_bf + uni_ + lo3, g3B + (BUF) * 8192 + (SET) * 4096 + ((w << 3) << 6)); \
    } while (0)

#define G3_RD_A(MQ, BUF) do { \
    _Pragma("unroll") for (int i = 0; i < 4; ++i) { \
        afr[i][0] = *(const bf16x8*)(gA0 + (BUF) * 32768 + (MQ) * 8192 + i * 2048); \
        afr[i][1] = *(const bf16x8*)(gA1 + (BUF) * 32768 + (MQ) * 8192 + i * 2048); \
    } } while (0)

#define G3_RD_B(BUF) do { \
    _Pragma("unroll") for (int n = 0; n < 2; ++n) { \
        bfr[n][0] = *(const bf16x8*)(gB0 + (BUF) * 16384 + n * 2048); \
        bfr[n][1] = *(const bf16x8*)(gB1 + (BUF) * 16384 + n * 2048); \
    } } while (0)

#define G3_MFMA(MQ) do { \
    _Pragma("unroll") for (int i = 0; i < 4; ++i) \
    _Pragma("unroll") for (int n = 0; n < 2; ++n) \
    _Pragma("unroll") for (int kk = 0; kk < 2; ++kk) \
        acc3[(MQ)*4+i][n] = __builtin_amdgcn_mfma_f32_16x16x32_bf16( \
            afr[i][kk], bfr[n][kk], acc3[(MQ)*4+i][n], 0, 0, 0); \
    } while (0)

#define DRAIN_FENCE() do { \
    asm volatile("s_waitcnt vmcnt(0) lgkmcnt(0)" ::: "memory"); \
    __threadfence(); \
    } while (0)

// ---------------------------------------------------------------------------
// Fused cooperative kernel: phase0 conversions -> gemm12 -> gemm3
// 256 blocks x 512 threads, 128 KB LDS -> exactly 1 block/CU co-resident
// ---------------------------------------------------------------------------
__global__ __launch_bounds__(512, 1) void fused_kernel(
    const float* __restrict__ x, const float* __restrict__ h,
    const float* __restrict__ W_in, const float* __restrict__ W_hh,
    const float* __restrict__ bh, const float* __restrict__ W_out,
    const float* __restrict__ bout,
    u16* __restrict__ x_bf, u16* __restrict__ h_bf,
    u16* __restrict__ win_bf, u16* __restrict__ whh_bf,
    u16* __restrict__ wout_bf, u16* __restrict__ hn_bf,
    float* __restrict__ hnew_f32, float* __restrict__ y,
    float* __restrict__ act_out) {
    __shared__ alignas(16) u16 lds[65536];  // 128 KB, reused across phases
    cg::grid_group grid = cg::this_grid();
    int orig = blockIdx.x, t = threadIdx.x;

    // ================= phase 0: conversions (uniform, no tail) =============
    {
        // h rows [orig*32, +32), thread handles cols t*4..t*4+3 (+ rec stats)
        float c0 = 0.f, c1 = 0.f, c2 = 0.f, c3 = 0.f;
        const float* hp = h + (size_t)(orig * 32) * 2048 + t * 4;
        u16* hbp = h_bf + (size_t)(orig * 32) * 2048 + t * 4;
#pragma unroll 8
        for (int r = 0; r < 32; ++r) {
            float4 a = *(const float4*)(hp + (size_t)r * 2048);
            ushort4 u;
            u.x = f2bf(a.x); u.y = f2bf(a.y); u.z = f2bf(a.z); u.w = f2bf(a.w);
            *(ushort4*)(hbp + (size_t)r * 2048) = u;
            c0 += (fabsf(a.x) > 0.1f) ? 1.f : 0.f;
            c1 += (fabsf(a.y) > 0.1f) ? 1.f : 0.f;
            c2 += (fabsf(a.z) > 0.1f) ? 1.f : 0.f;
            c3 += (fabsf(a.w) > 0.1f) ? 1.f : 0.f;
        }
        atomicAdd(&act_out[2048 + t * 4 + 0], c0 * (1.0f / 8192.0f));
        atomicAdd(&act_out[2048 + t * 4 + 1], c1 * (1.0f / 8192.0f));
        atomicAdd(&act_out[2048 + t * 4 + 2], c2 * (1.0f / 8192.0f));
        atomicAdd(&act_out[2048 + t * 4 + 3], c3 * (1.0f / 8192.0f));

        // x/W_in/W_hh/W_out: 2,097,152 8-elem groups / 131072 threads = 16 each
        int base = orig * 512 + t;
#pragma unroll 4
        for (int k = 0; k < 16; ++k) {
            int g = base + k * 131072;
            const float* src; u16* dst; int off;
            if (g < 1048576)       { src = x;     dst = x_bf;    off = g; }
            else if (g < 1310720)  { src = W_in;  dst = win_bf;  off = g - 1048576; }
            else if (g < 1835008)  { src = W_hh;  dst = whh_bf;  off = g - 1310720; }
            else                   { src = W_out; dst = wout_bf; off = g - 1835008; }
            const float4* p = (const float4*)src + (size_t)off * 2;
            float4 a = p[0], bb = p[1];
            U8 u;
            u.v[0] = f2bf(a.x);  u.v[1] = f2bf(a.y);  u.v[2] = f2bf(a.z);  u.v[3] = f2bf(a.w);
            u.v[4] = f2bf(bb.x); u.v[5] = f2bf(bb.y); u.v[6] = f2bf(bb.z); u.v[7] = f2bf(bb.w);
            *(U8*)(dst + (size_t)off * 8) = u;
        }
    }
    DRAIN_FENCE();
    grid.sync();

    // ================= phase 1: gemm12 (frozen structure) ==================
    {
        u16* Alds = lds;
        u16* Blds = lds + 32768;
        int wg = (orig & 7) * 32 + (orig >> 3);    // XCD swizzle
        int bm = wg >> 3, bn = wg & 7;
        int lane = t & 63, w = t >> 6;
        int wm = w >> 2, wn = w & 3;
        int l15 = lane & 15, hi = lane >> 4;
        int rbA = bm << 8, rbB = bn << 8;

        int r0 = t >> 3, c8 = t & 7;
        int swz = (c8 ^ (r0 & 7)) << 3;
        int arB0 = ((r0 >> 5) << 6) + (r0 & 31);
        int loA1 = (r0 << 10) + swz, loA2 = (r0 << 11) + swz;
        int loB1 = (arB0 << 10) + swz, loB2 = (arB0 << 11) + swz;

        int cb0 = (hi ^ (l15 & 7)) << 4;
        int cb1 = ((4 + hi) ^ (l15 & 7)) << 4;
        const char* fA0 = (const char*)(Alds + (((wm << 7) + l15) << 6)) + cb0;
        const char* fA1 = (const char*)(Alds + (((wm << 7) + l15) << 6)) + cb1;
        const char* fB0 = (const char*)(Blds + (((wn << 6) + l15) << 6)) + cb0;
        const char* fB1 = (const char*)(Blds + (((wn << 6) + l15) << 6)) + cb1;

        f32x4 acc[8][4];
#pragma unroll
        for (int i = 0; i < 8; ++i)
#pragma unroll
            for (int j = 0; j < 4; ++j) acc[i][j] = (f32x4){0.f, 0.f, 0.f, 0.f};
        bf16x8 afr[4][2], bfr[4][2];

        {
            SegU s0 = segu(0, x_bf, win_bf, h_bf, whh_bf, rbA, rbB, loA1, loA2, loB1, loB2);
            SegU s1 = segu(1, x_bf, win_bf, h_bf, whh_bf, rbA, rbB, loA1, loA2, loB1, loB2);
            STA(s0, 0, 0); STB(s0, 0, 0);
            STA(s0, 1, 0); STB(s0, 1, 0);
            STA(s1, 0, 1); STB(s1, 0, 1);
        }
        asm volatile("s_waitcnt vmcnt(4)" ::: "memory");
        asm volatile("s_barrier" ::: "memory");

        for (int it = 0; it < 24; ++it) {
            int tb = it << 1;
            int t2 = tb + 2 < 47 ? tb + 2 : 47;
            int t3 = tb + 3 < 47 ? tb + 3 : 47;
            SegU s1 = segu(tb + 1, x_bf, win_bf, h_bf, whh_bf, rbA, rbB, loA1, loA2, loB1, loB2);
            SegU s2 = segu(t2,     x_bf, win_bf, h_bf, whh_bf, rbA, rbB, loA1, loA2, loB1, loB2);
            SegU s3 = segu(t3,     x_bf, win_bf, h_bf, whh_bf, rbA, rbB, loA1, loA2, loB1, loB2);

            RD_B_ALL(0); RD_A(0, 0);
            STA(s1, 1, 1); STB(s1, 1, 1);
            PHASE_MID(); MFMA_M(0); BAREND();
            RD_A(1, 0);
            STA(s2, 0, 0); STB(s2, 0, 0);
            PHASE_MID(); MFMA_M(1); BAREND_VM();
            RD_B_ALL(1); RD_A(0, 1);
            STA(s2, 1, 0); STB(s2, 1, 0);
            PHASE_MID(); MFMA_M(0); BAREND();
            RD_A(1, 1);
            STA(s3, 0, 1); STB(s3, 0, 1);
            PHASE_MID(); MFMA_M(1); BAREND_VM();
        }

        const int row0 = (bm << 8) + (wm << 7);
        const int col0 = (bn << 8) + (wn << 6);
#pragma unroll
        for (int n = 0; n < 4; ++n) {
            int col = col0 + (n << 4) + l15;
            float bhv = bh[col];
            float csum = 0.f;
#pragma unroll
            for (int m = 0; m < 8; ++m) {
#pragma unroll
                for (int r = 0; r < 4; ++r) {
                    int row = row0 + (m << 4) + (hi << 2) + r;
                    float v = fmaxf(acc[m][n][r] + bhv, 0.f);
                    size_t off = (size_t)row * 2048 + col;
                    hnew_f32[off] = v;
                    hn_bf[off] = f2bf(v);
                    csum += v;
                }
            }
            csum += __shfl_xor(csum, 16, 64);
            csum += __shfl_xor(csum, 32, 64);
            if (lane < 16) atomicAdd(&act_out[col], csum * (1.0f / 8192.0f));
        }
    }
    DRAIN_FENCE();
    grid.sync();

    // ================= phase 2: gemm3 (frozen structure) ===================
    {
        u16* g3A = lds;
        u16* g3B = lds + 32768;
        int wg = (orig & 7) * 32 + (orig >> 3);
        int bm = wg >> 3, bn = wg & 7;
        int lane = t & 63, w = t >> 6;
        int wm = w >> 2, wn = w & 3;
        int l15 = lane & 15, hi = lane >> 4;

        int r0 = t >> 3, c8 = t & 7;
        int swz = (c8 ^ (r0 & 7)) << 3;
        int lo3 = (r0 << 11) + swz;
        int uA3 = (bm << 8) << 11;
        int uB3 = (bn << 7) << 11;

        int cb0 = (hi ^ (l15 & 7)) << 4;
        int cb1 = ((4 + hi) ^ (l15 & 7)) << 4;
        const char* gA0 = (const char*)(g3A + (((wm << 7) + l15) << 6)) + cb0;
        const char* gA1 = (const char*)(g3A + (((wm << 7) + l15) << 6)) + cb1;
        const char* gB0 = (const char*)(g3B + (((wn << 5) + l15) << 6)) + cb0;
        const char* gB1 = (const char*)(g3B + (((wn << 5) + l15) << 6)) + cb1;

        f32x4 acc3[8][2];
#pragma unroll
        for (int i = 0; i < 8; ++i)
#pragma unroll
            for (int j = 0; j < 2; ++j) acc3[i][j] = (f32x4){0.f, 0.f, 0.f, 0.f};
        bf16x8 afr[4][2], bfr[2][2];

        G3_STA(0, 0, 0); G3_STB(0, 0, 0);
        G3_STA(0, 1, 0); G3_STB(0, 1, 0);
        G3_STA(1, 0, 1); G3_STB(1, 0, 1);
        asm volatile("s_waitcnt vmcnt(3)" ::: "memory");
        asm volatile("s_barrier" ::: "memory");

        for (int it = 0; it < 16; ++it) {
            int tb = it << 1;
            int t2 = tb + 2 < 31 ? tb + 2 : 31;
            int t3 = tb + 3 < 31 ? tb + 3 : 31;
            int t1 = tb + 1;

            G3_RD_B(0); G3_RD_A(0, 0);
            G3_STA(t1, 1, 1); G3_STB(t1, 1, 1);
            PHASE_MID(); G3_MFMA(0); BAREND();
            G3_RD_A(1, 0);
            G3_STA(t2, 0, 0); G3_STB(t2, 0, 0);
            PHASE_MID(); G3_MFMA(1); BAREND_VM3();
            G3_RD_B(1); G3_RD_A(0, 1);
            G3_STA(t2, 1, 0); G3_STB(t2, 1, 0);
            PHASE_MID(); G3_MFMA(0); BAREND();
            G3_RD_A(1, 1);
            G3_STA(t3, 0, 1); G3_STB(t3, 0, 1);
            PHASE_MID(); G3_MFMA(1); BAREND_VM3();
        }

        const int row0 = (bm << 8) + (wm << 7);
        const int col0 = (bn << 7) + (wn << 5);
#pragma unroll
        for (int n = 0; n < 2; ++n) {
            int col = col0 + (n << 4) + l15;
            float bv = bout[col];
#pragma unroll
            for (int m = 0; m < 8; ++m) {
#pragma unroll
                for (int r = 0; r < 4; ++r) {
                    int row = row0 + (m << 4) + (hi << 2) + r;
                    y[(size_t)row * 1024 + col] = acc3[m][n][r] + bv;
                }
            }
        }
    }
}

// ---------------------------------------------------------------------------
extern "C" void kernel_launch(void* const* d_in, const int* in_sizes, int n_in,
                              void* d_out, int out_size, void* d_ws, size_t ws_size,
                              hipStream_t stream) {
    const float* x     = (const float*)d_in[0];
    const float* h     = (const float*)d_in[1];
    const float* W_in  = (const float*)d_in[2];
    const float* W_hh  = (const float*)d_in[3];
    const float* b_h   = (const float*)d_in[4];
    const float* W_out = (const float*)d_in[5];
    const float* b_out = (const float*)d_in[6];

    float* out  = (float*)d_out;
    float* y    = out;
    float* hnew = out + 8388608;
    float* act  = out + 8388608 + 16777216;

    char* ws = (char*)d_ws;
    u16* x_bf    = (u16*)(ws);
    u16* h_bf    = (u16*)(ws + (16ull << 20));
    u16* win_bf  = (u16*)(ws + (48ull << 20));
    u16* whh_bf  = (u16*)(ws + (52ull << 20));
    u16* wout_bf = (u16*)(ws + (60ull << 20));
    u16* hn_bf   = (u16*)(ws + (64ull << 20));

    hipMemsetAsync(act, 0, 4096 * sizeof(float), stream);

    void* args[] = {
        (void*)&x, (void*)&h, (void*)&W_in, (void*)&W_hh, (void*)&b_h,
        (void*)&W_out, (void*)&b_out,
        (void*)&x_bf, (void*)&h_bf, (void*)&win_bf, (void*)&whh_bf,
        (void*)&wout_bf, (void*)&hn_bf,
        (void*)&hnew, (void*)&y, (void*)&act
    };
    hipLaunchCooperativeKernel((const void*)fused_kernel, dim3(256), dim3(512),
                               args, 0, stream);
}

// Round 18
// 225.422 us; speedup vs baseline: 1.8226x; 1.8226x over previous
//
#include <hip/hip_runtime.h>
#include <hip/hip_bf16.h>

typedef unsigned short u16;
typedef __attribute__((ext_vector_type(8))) short bf16x8;
typedef __attribute__((ext_vector_type(4))) float f32x4;

#define DEVINL __device__ __forceinline__

struct alignas(16) U8 { u16 v[8]; };

DEVINL u16 f2bf(float f) {
    unsigned int x = __float_as_uint(f);
    unsigned int r = (x + 0x7fffu + ((x >> 16) & 1u)) >> 16;
    return (u16)r;
}

DEVINL void gload_lds16(const void* g, void* l) {
    __builtin_amdgcn_global_load_lds(
        (const __attribute__((address_space(1))) void*)g,
        (__attribute__((address_space(3))) void*)l,
        16, 0, 0);
}

// ---------------------------------------------------------------------------
// conversion kernel v2: blocks 0..255 = h (32 rows each, launched FIRST);
// blocks 256..8447 = x/W_in/W_hh/W_out light blocks
// ---------------------------------------------------------------------------
__global__ __launch_bounds__(256) void cvt_all_kernel(
    const float* __restrict__ x, u16* __restrict__ xb,
    const float* __restrict__ wi, u16* __restrict__ wib,
    const float* __restrict__ wh, u16* __restrict__ whb,
    const float* __restrict__ wo, u16* __restrict__ wob,
    const float* __restrict__ h, u16* __restrict__ hbf,
    float* __restrict__ rec_out) {
    int b = blockIdx.x;
    int t = threadIdx.x;
    if (b < 256) {
        float cnt[8] = {0.f, 0.f, 0.f, 0.f, 0.f, 0.f, 0.f, 0.f};
        for (int r = 0; r < 32; ++r) {
            size_t off = ((size_t)(b * 32 + r)) * 2048 + t * 8;
            float4 a = *(const float4*)(h + off);
            float4 bb = *(const float4*)(h + off + 4);
            float vv[8] = {a.x, a.y, a.z, a.w, bb.x, bb.y, bb.z, bb.w};
            U8 u;
#pragma unroll
            for (int j = 0; j < 8; ++j) {
                u.v[j] = f2bf(vv[j]);
                cnt[j] += (fabsf(vv[j]) > 0.1f) ? 1.f : 0.f;
            }
            *(U8*)(hbf + off) = u;
        }
#pragma unroll
        for (int j = 0; j < 8; ++j)
            atomicAdd(&rec_out[t * 8 + j], cnt[j] * (1.0f / 8192.0f));
    } else {
        int i = (b - 256) * 256 + t;
        const float* src; u16* dst; int off;
        if (i < 1048576)       { src = x;  dst = xb;  off = i; }
        else if (i < 1310720)  { src = wi; dst = wib; off = i - 1048576; }
        else if (i < 1835008)  { src = wh; dst = whb; off = i - 1310720; }
        else                   { src = wo; dst = wob; off = i - 1835008; }
        const float4* p = (const float4*)src + (size_t)off * 2;
        float4 a = p[0], bb = p[1];
        U8 u;
        u.v[0] = f2bf(a.x);  u.v[1] = f2bf(a.y);  u.v[2] = f2bf(a.z);  u.v[3] = f2bf(a.w);
        u.v[4] = f2bf(bb.x); u.v[5] = f2bf(bb.y); u.v[6] = f2bf(bb.z); u.v[7] = f2bf(bb.w);
        *(U8*)(dst + (size_t)off * 8) = u;
    }
}

// ---------------------------------------------------------------------------
// staging helpers with hoisted addressing
// ---------------------------------------------------------------------------
DEVINL void stA(const u16* p, int uni, int lo, int ld, u16* dst, int w) {
    gload_lds16(p + uni + lo, dst + ((w << 3) << 6));
    gload_lds16(p + uni + lo + (ld << 7), dst + ((128 + (w << 3)) << 6));
}
DEVINL void stB(const u16* p, int uni, int lo, int ld, u16* dst, int w) {
    int d0 = ((w >> 2) << 6) + ((w & 3) << 3);
    gload_lds16(p + uni + lo, dst + (d0 << 6));
    gload_lds16(p + uni + lo + (ld << 7), dst + ((128 + d0) << 6));
}

// segment info for concatenated K (tiles 0-15: x/W_in, 16-47: h/W_hh)
struct SegU { const u16* pA; const u16* pB; int uA; int uB; int ld; int loA; int loB; };

DEVINL SegU segu(int kt, const u16* X, const u16* W1, const u16* H, const u16* W2,
                 int rbA, int rbB, int loA1, int loA2, int loB1, int loB2) {
    SegU s;
    if (kt < 16) {
        int k0 = kt << 6;
        s.pA = X; s.pB = W1; s.ld = 1024;
        s.uA = (rbA << 10) + k0; s.uB = (rbB << 10) + k0;
        s.loA = loA1; s.loB = loB1;
    } else {
        int k0 = (kt - 16) << 6;
        s.pA = H; s.pB = W2; s.ld = 2048;
        s.uA = (rbA << 11) + k0; s.uB = (rbB << 11) + k0;
        s.loA = loA2; s.loB = loB2;
    }
    return s;
}

#define STA(S, SET, BUF) stA((S).pA, (S).uA + ((SET) ? ((S).ld << 6) : 0), (S).loA, \
                             (S).ld, Alds + (BUF) * 16384 + (SET) * 4096, w)
#define STB(S, SET, BUF) stB((S).pB, (S).uB + ((SET) ? ((S).ld << 5) : 0), (S).loB, \
                             (S).ld, Blds + (BUF) * 16384 + (SET) * 2048, w)

// fragment reads: single VGPR base + compile-time byte imm
#define RD_A(MQ, BUF) do { \
    _Pragma("unroll") for (int i = 0; i < 4; ++i) { \
        afr[i][0] = *(const bf16x8*)(fA0 + (BUF) * 32768 + (MQ) * 8192 + i * 2048); \
        afr[i][1] = *(const bf16x8*)(fA1 + (BUF) * 32768 + (MQ) * 8192 + i * 2048); \
    } } while (0)

#define RD_B_ALL(BUF) do { \
    _Pragma("unroll") for (int n = 0; n < 4; ++n) { \
        bfr[n][0] = *(const bf16x8*)(fB0 + (BUF) * 32768 + n * 2048); \
        bfr[n][1] = *(const bf16x8*)(fB1 + (BUF) * 32768 + n * 2048); \
    } } while (0)

// 32 MFMA: one m-half x all n x both K-halves
#define MFMA_M(MQ) do { \
    _Pragma("unroll") for (int i = 0; i < 4; ++i) \
    _Pragma("unroll") for (int n = 0; n < 4; ++n) \
    _Pragma("unroll") for (int kk = 0; kk < 2; ++kk) \
        acc[(MQ)*4+i][n] = __builtin_amdgcn_mfma_f32_16x16x32_bf16( \
            afr[i][kk], bfr[n][kk], acc[(MQ)*4+i][n], 0, 0, 0); \
    } while (0)

// NO leading barrier: per-wave lgkm drain only -> waves slip within a phase,
// LDS reads of slow waves overlap MFMA of fast waves. Trailing barrier keeps
// all cross-phase WAR ordering (reads complete before own lgkm0 -> before bar).
#define PHASE_MID() do { \
    asm volatile("s_waitcnt lgkmcnt(0)" ::: "memory"); \
    __builtin_amdgcn_sched_barrier(0); \
    __builtin_amdgcn_s_setprio(1); \
    } while (0)

#define BAREND() do { \
    __builtin_amdgcn_s_setprio(0); \
    __builtin_amdgcn_sched_barrier(0); \
    asm volatile("s_barrier" ::: "memory"); \
    } while (0)

#define BAREND_VM() do { \
    __builtin_amdgcn_s_setprio(0); \
    __builtin_amdgcn_sched_barrier(0); \
    asm volatile("s_waitcnt vmcnt(4)" ::: "memory"); \
    asm volatile("s_barrier" ::: "memory"); \
    } while (0)

#define BAREND_VM3() do { \
    __builtin_amdgcn_s_setprio(0); \
    __builtin_amdgcn_sched_barrier(0); \
    asm volatile("s_waitcnt vmcnt(3)" ::: "memory"); \
    asm volatile("s_barrier" ::: "memory"); \
    } while (0)

// ---------------------------------------------------------------------------
// GEMM12, 256x256 tile, 8-wave, 2-phases-per-K-tile counted-vmcnt pipeline,
// single trailing barrier per phase.
// ---------------------------------------------------------------------------
__global__ __launch_bounds__(512, 2) void gemm12_k8(
    const u16* __restrict__ Xbf, const u16* __restrict__ Win,
    const u16* __restrict__ Hbf, const u16* __restrict__ Whh,
    const float* __restrict__ bh,
    float* __restrict__ hnew_f32, u16* __restrict__ hnew_bf,
    float* __restrict__ act_out) {
    __shared__ alignas(16) u16 lds[4][16384];  // [A0|A1|B0|B1] = 128 KB
    u16* Alds = &lds[0][0];
    u16* Blds = &lds[2][0];
    int orig = blockIdx.x;
    int wg = (orig & 7) * 32 + (orig >> 3);    // XCD swizzle (256 % 8 == 0)
    int bm = wg >> 3, bn = wg & 7;
    int t = threadIdx.x, lane = t & 63, w = t >> 6;
    int wm = w >> 2, wn = w & 3;
    int l15 = lane & 15, hi = lane >> 4;
    int rbA = bm << 8, rbB = bn << 8;

    // invariant staging lane offsets
    int r0 = t >> 3, c8 = t & 7;
    int swz = (c8 ^ (r0 & 7)) << 3;
    int arB0 = ((r0 >> 5) << 6) + (r0 & 31);
    int loA1 = (r0 << 10) + swz, loA2 = (r0 << 11) + swz;
    int loB1 = (arB0 << 10) + swz, loB2 = (arB0 << 11) + swz;

    // fragment base pointers (swizzle term depends only on l15&7)
    int cb0 = (hi ^ (l15 & 7)) << 4;
    int cb1 = ((4 + hi) ^ (l15 & 7)) << 4;
    const char* fA0 = (const char*)(Alds + (((wm << 7) + l15) << 6)) + cb0;
    const char* fA1 = (const char*)(Alds + (((wm << 7) + l15) << 6)) + cb1;
    const char* fB0 = (const char*)(Blds + (((wn << 6) + l15) << 6)) + cb0;
    const char* fB1 = (const char*)(Blds + (((wn << 6) + l15) << 6)) + cb1;

    f32x4 acc[8][4];
#pragma unroll
    for (int i = 0; i < 8; ++i)
#pragma unroll
        for (int j = 0; j < 4; ++j) acc[i][j] = (f32x4){0.f, 0.f, 0.f, 0.f};
    bf16x8 afr[4][2], bfr[4][2];

    // prologue: tile0 all 4 sets + tile1 set0 (A,B) = 12 loads; wait to <=4
    {
        SegU s0 = segu(0, Xbf, Win, Hbf, Whh, rbA, rbB, loA1, loA2, loB1, loB2);
        SegU s1 = segu(1, Xbf, Win, Hbf, Whh, rbA, rbB, loA1, loA2, loB1, loB2);
        STA(s0, 0, 0); STB(s0, 0, 0);
        STA(s0, 1, 0); STB(s0, 1, 0);
        STA(s1, 0, 1); STB(s1, 0, 1);
    }
    asm volatile("s_waitcnt vmcnt(4)" ::: "memory");
    asm volatile("s_barrier" ::: "memory");

    for (int it = 0; it < 24; ++it) {
        int tb = it << 1;
        int t2 = tb + 2 < 47 ? tb + 2 : 47;
        int t3 = tb + 3 < 47 ? tb + 3 : 47;
        SegU s1 = segu(tb + 1, Xbf, Win, Hbf, Whh, rbA, rbB, loA1, loA2, loB1, loB2);
        SegU s2 = segu(t2,     Xbf, Win, Hbf, Whh, rbA, rbB, loA1, loA2, loB1, loB2);
        SegU s3 = segu(t3,     Xbf, Win, Hbf, Whh, rbA, rbB, loA1, loA2, loB1, loB2);

        // phase A: tile tb (buf0), m0; stage (tb+1,set1)->buf1
        RD_B_ALL(0); RD_A(0, 0);
        STA(s1, 1, 1); STB(s1, 1, 1);
        PHASE_MID(); MFMA_M(0); BAREND();
        // phase B: tile tb, m1; stage (tb+2,set0)->buf0
        RD_A(1, 0);
        STA(s2, 0, 0); STB(s2, 0, 0);
        PHASE_MID(); MFMA_M(1); BAREND_VM();
        // phase C: tile tb+1 (buf1), m0; stage (tb+2,set1)->buf0
        RD_B_ALL(1); RD_A(0, 1);
        STA(s2, 1, 0); STB(s2, 1, 0);
        PHASE_MID(); MFMA_M(0); BAREND();
        // phase D: tile tb+1, m1; stage (tb+3,set0)->buf1
        RD_A(1, 1);
        STA(s3, 0, 1); STB(s3, 0, 1);
        PHASE_MID(); MFMA_M(1); BAREND_VM();
    }

    // epilogue: bias + relu + stores + act column sums
    const int row0 = (bm << 8) + (wm << 7);
    const int col0 = (bn << 8) + (wn << 6);
#pragma unroll
    for (int n = 0; n < 4; ++n) {
        int col = col0 + (n << 4) + l15;
        float bhv = bh[col];
        float csum = 0.f;
#pragma unroll
        for (int m = 0; m < 8; ++m) {
#pragma unroll
            for (int r = 0; r < 4; ++r) {
                int row = row0 + (m << 4) + (hi << 2) + r;
                float v = fmaxf(acc[m][n][r] + bhv, 0.f);
                size_t off = (size_t)row * 2048 + col;
                hnew_f32[off] = v;
                hnew_bf[off] = f2bf(v);
                csum += v;
            }
        }
        csum += __shfl_xor(csum, 16, 64);
        csum += __shfl_xor(csum, 32, 64);
        if (lane < 16) atomicAdd(&act_out[col], csum * (1.0f / 8192.0f));
    }
}

// ---------------------------------------------------------------------------
// GEMM3: y = h_new@W_out.T + b_out (256x128 tile, 8 waves, counted vmcnt,
// single trailing barrier per phase)
// ---------------------------------------------------------------------------
#define G3_STA(KT, SET, BUF) do { \
    int uni_ = uA + ((KT) << 6) + ((SET) ? (2048 << 6) : 0); \
    u16* dst_ = g3A + (BUF) * 16384 + (SET) * 4096; \
    gload_lds16(Hn + uni_ + lo, dst_ + ((w << 3) << 6)); \
    gload_lds16(Hn + uni_ + lo + (2048 << 7), dst_ + ((128 + (w << 3)) << 6)); \
    } while (0)

#define G3_STB(KT, SET, BUF) do { \
    int uni_ = uB + ((KT) << 6) + ((SET) ? (2048 << 6) : 0); \
    gload_lds16(Wout + uni_ + lo, g3B + (BUF) * 8192 + (SET) * 4096 + ((w << 3) << 6)); \
    } while (0)

#define G3_RD_A(MQ, BUF) do { \
    _Pragma("unroll") for (int i = 0; i < 4; ++i) { \
        afr[i][0] = *(const bf16x8*)(fA0 + (BUF) * 32768 + (MQ) * 8192 + i * 2048); \
        afr[i][1] = *(const bf16x8*)(fA1 + (BUF) * 32768 + (MQ) * 8192 + i * 2048); \
    } } while (0)

#define G3_RD_B(BUF) do { \
    _Pragma("unroll") for (int n = 0; n < 2; ++n) { \
        bfr[n][0] = *(const bf16x8*)(fB0 + (BUF) * 16384 + n * 2048); \
        bfr[n][1] = *(const bf16x8*)(fB1 + (BUF) * 16384 + n * 2048); \
    } } while (0)

#define G3_MFMA(MQ) do { \
    _Pragma("unroll") for (int i = 0; i < 4; ++i) \
    _Pragma("unroll") for (int n = 0; n < 2; ++n) \
    _Pragma("unroll") for (int kk = 0; kk < 2; ++kk) \
        acc[(MQ)*4+i][n] = __builtin_amdgcn_mfma_f32_16x16x32_bf16( \
            afr[i][kk], bfr[n][kk], acc[(MQ)*4+i][n], 0, 0, 0); \
    } while (0)

__global__ __launch_bounds__(512, 1) void gemm3_k8(
    const u16* __restrict__ Hn, const u16* __restrict__ Wout,
    const float* __restrict__ bout, float* __restrict__ y) {
    __shared__ alignas(16) u16 lds[49152];  // A: 2x16384, B: 2x8192 = 96 KB
    u16* g3A = &lds[0];
    u16* g3B = &lds[32768];
    int orig = blockIdx.x;
    int wg = (orig & 7) * 32 + (orig >> 3);   // XCD swizzle (256 % 8 == 0)
    int bm = wg >> 3, bn = wg & 7;            // 32 x 8
    int t = threadIdx.x, lane = t & 63, w = t >> 6;
    int wm = w >> 2, wn = w & 3;
    int l15 = lane & 15, hi = lane >> 4;

    // staging lane offsets (both operands lda=2048)
    int r0 = t >> 3, c8 = t & 7;
    int swz = (c8 ^ (r0 & 7)) << 3;
    int lo = (r0 << 11) + swz;
    int uA = (bm << 8) << 11;   // bm*256*2048
    int uB = (bn << 7) << 11;   // bn*128*2048

    // fragment bases
    int cb0 = (hi ^ (l15 & 7)) << 4;
    int cb1 = ((4 + hi) ^ (l15 & 7)) << 4;
    const char* fA0 = (const char*)(g3A + (((wm << 7) + l15) << 6)) + cb0;
    const char* fA1 = (const char*)(g3A + (((wm << 7) + l15) << 6)) + cb1;
    const char* fB0 = (const char*)(g3B + (((wn << 5) + l15) << 6)) + cb0;
    const char* fB1 = (const char*)(g3B + (((wn << 5) + l15) << 6)) + cb1;

    f32x4 acc[8][2];
#pragma unroll
    for (int i = 0; i < 8; ++i)
#pragma unroll
        for (int j = 0; j < 2; ++j) acc[i][j] = (f32x4){0.f, 0.f, 0.f, 0.f};
    bf16x8 afr[4][2], bfr[2][2];

    // prologue: tile0 full (6 loads) + tile1 set0 (3 loads); wait to <=3
    G3_STA(0, 0, 0); G3_STB(0, 0, 0);
    G3_STA(0, 1, 0); G3_STB(0, 1, 0);
    G3_STA(1, 0, 1); G3_STB(1, 0, 1);
    asm volatile("s_waitcnt vmcnt(3)" ::: "memory");
    asm volatile("s_barrier" ::: "memory");

    for (int it = 0; it < 16; ++it) {
        int tb = it << 1;
        int t2 = tb + 2 < 31 ? tb + 2 : 31;
        int t3 = tb + 3 < 31 ? tb + 3 : 31;
        int t1 = tb + 1;

        // phase A: tile tb (buf0), m0; stage (tb+1,set1)->buf1
        G3_RD_B(0); G3_RD_A(0, 0);
        G3_STA(t1, 1, 1); G3_STB(t1, 1, 1);
        PHASE_MID(); G3_MFMA(0); BAREND();
        // phase B: tile tb, m1; stage (tb+2,set0)->buf0
        G3_RD_A(1, 0);
        G3_STA(t2, 0, 0); G3_STB(t2, 0, 0);
        PHASE_MID(); G3_MFMA(1); BAREND_VM3();
        // phase C: tile tb+1 (buf1), m0; stage (tb+2,set1)->buf0
        G3_RD_B(1); G3_RD_A(0, 1);
        G3_STA(t2, 1, 0); G3_STB(t2, 1, 0);
        PHASE_MID(); G3_MFMA(0); BAREND();
        // phase D: tile tb+1, m1; stage (tb+3,set0)->buf1
        G3_RD_A(1, 1);
        G3_STA(t3, 0, 1); G3_STB(t3, 0, 1);
        PHASE_MID(); G3_MFMA(1); BAREND_VM3();
    }

    const int row0 = (bm << 8) + (wm << 7);
    const int col0 = (bn << 7) + (wn << 5);
#pragma unroll
    for (int n = 0; n < 2; ++n) {
        int col = col0 + (n << 4) + l15;
        float bv = bout[col];
#pragma unroll
        for (int m = 0; m < 8; ++m) {
#pragma unroll
            for (int r = 0; r < 4; ++r) {
                int row = row0 + (m << 4) + (hi << 2) + r;
                y[(size_t)row * 1024 + col] = acc[m][n][r] + bv;
            }
        }
    }
}

// ---------------------------------------------------------------------------
extern "C" void kernel_launch(void* const* d_in, const int* in_sizes, int n_in,
                              void* d_out, int out_size, void* d_ws, size_t ws_size,
                              hipStream_t stream) {
    const float* x     = (const float*)d_in[0];
    const float* h     = (const float*)d_in[1];
    const float* W_in  = (const float*)d_in[2];
    const float* W_hh  = (const float*)d_in[3];
    const float* b_h   = (const float*)d_in[4];
    const float* W_out = (const float*)d_in[5];
    const float* b_out = (const float*)d_in[6];

    float* out  = (float*)d_out;
    float* y    = out;
    float* hnew = out + 8388608;
    float* act  = out + 8388608 + 16777216;

    char* ws = (char*)d_ws;
    u16* x_bf    = (u16*)(ws);
    u16* h_bf    = (u16*)(ws + (16ull << 20));
    u16* win_bf  = (u16*)(ws + (48ull << 20));
    u16* whh_bf  = (u16*)(ws + (52ull << 20));
    u16* wout_bf = (u16*)(ws + (60ull << 20));
    u16* hn_bf   = (u16*)(ws + (64ull << 20));

    hipMemsetAsync(act, 0, 4096 * sizeof(float), stream);

    cvt_all_kernel<<<8448, 256, 0, stream>>>(x, x_bf, W_in, win_bf, W_hh, whh_bf,
                                             W_out, wout_bf, h, h_bf, act + 2048);

    gemm12_k8<<<256, 512, 0, stream>>>(x_bf, win_bf, h_bf, whh_bf, b_h,
                                       hnew, hn_bf, act);
    gemm3_k8<<<256, 512, 0, stream>>>(hn_bf, wout_bf, b_out, y);
}

// Round 19
// 181.048 us; speedup vs baseline: 2.2694x; 1.2451x over previous
//
#include <hip/hip_runtime.h>
#include <hip/hip_bf16.h>

typedef unsigned short u16;
typedef __attribute__((ext_vector_type(8))) short bf16x8;
typedef __attribute__((ext_vector_type(4))) float f32x4;

#define DEVINL __device__ __forceinline__

struct alignas(16) U8 { u16 v[8]; };

DEVINL u16 f2bf(float f) {
    unsigned int x = __float_as_uint(f);
    unsigned int r = (x + 0x7fffu + ((x >> 16) & 1u)) >> 16;
    return (u16)r;
}

DEVINL void gload_lds16(const void* g, void* l) {
    __builtin_amdgcn_global_load_lds(
        (const __attribute__((address_space(1))) void*)g,
        (__attribute__((address_space(3))) void*)l,
        16, 0, 0);
}

// ---------------------------------------------------------------------------
// conversion kernel v3: blocks 0..255 = h (32 rows each, FIRST, partial counts
// to workspace -> NO atomics); blocks 256..8447 = x/W_in/W_hh/W_out
// ---------------------------------------------------------------------------
__global__ __launch_bounds__(256) void cvt_all_kernel(
    const float* __restrict__ x, u16* __restrict__ xb,
    const float* __restrict__ wi, u16* __restrict__ wib,
    const float* __restrict__ wh, u16* __restrict__ whb,
    const float* __restrict__ wo, u16* __restrict__ wob,
    const float* __restrict__ h, u16* __restrict__ hbf,
    float* __restrict__ partial) {
    int b = blockIdx.x;
    int t = threadIdx.x;
    if (b < 256) {
        float cnt[8] = {0.f, 0.f, 0.f, 0.f, 0.f, 0.f, 0.f, 0.f};
#pragma unroll 4
        for (int r = 0; r < 32; ++r) {
            size_t off = ((size_t)(b * 32 + r)) * 2048 + t * 8;
            float4 a = *(const float4*)(h + off);
            float4 bb = *(const float4*)(h + off + 4);
            float vv[8] = {a.x, a.y, a.z, a.w, bb.x, bb.y, bb.z, bb.w};
            U8 u;
#pragma unroll
            for (int j = 0; j < 8; ++j) {
                u.v[j] = f2bf(vv[j]);
                cnt[j] += (fabsf(vv[j]) > 0.1f) ? 1.f : 0.f;
            }
            *(U8*)(hbf + off) = u;
        }
        // coalesced partial write: partial[b][t*8 .. t*8+7]
        float4 p0 = {cnt[0], cnt[1], cnt[2], cnt[3]};
        float4 p1 = {cnt[4], cnt[5], cnt[6], cnt[7]};
        *(float4*)(partial + (size_t)b * 2048 + t * 8) = p0;
        *(float4*)(partial + (size_t)b * 2048 + t * 8 + 4) = p1;
    } else {
        int i = (b - 256) * 256 + t;
        const float* src; u16* dst; int off;
        if (i < 1048576)       { src = x;  dst = xb;  off = i; }
        else if (i < 1310720)  { src = wi; dst = wib; off = i - 1048576; }
        else if (i < 1835008)  { src = wh; dst = whb; off = i - 1310720; }
        else                   { src = wo; dst = wob; off = i - 1835008; }
        const float4* p = (const float4*)src + (size_t)off * 2;
        float4 a = p[0], bb = p[1];
        U8 u;
        u.v[0] = f2bf(a.x);  u.v[1] = f2bf(a.y);  u.v[2] = f2bf(a.z);  u.v[3] = f2bf(a.w);
        u.v[4] = f2bf(bb.x); u.v[5] = f2bf(bb.y); u.v[6] = f2bf(bb.z); u.v[7] = f2bf(bb.w);
        *(U8*)(dst + (size_t)off * 8) = u;
    }
}

// ---------------------------------------------------------------------------
// rec_reduce: sum 256 slices -> rec_out (direct store, no atomics)
// 32 blocks x 256 thr; wave v handles 64 cols; coalesced row reads
// ---------------------------------------------------------------------------
__global__ __launch_bounds__(256) void rec_reduce_kernel(
    const float* __restrict__ partial, float* __restrict__ rec_out) {
    __shared__ float red[4][64];
    int b = blockIdx.x, t = threadIdx.x;
    int col = (b << 6) + (t & 63);
    int sc = t >> 6;  // slice chunk 0..3 (64 slices each)
    float s = 0.f;
#pragma unroll 8
    for (int i = 0; i < 64; ++i)
        s += partial[(size_t)(sc * 64 + i) * 2048 + col];
    red[sc][t & 63] = s;
    __syncthreads();
    if (t < 64)
        rec_out[(b << 6) + t] =
            (red[0][t] + red[1][t] + red[2][t] + red[3][t]) * (1.0f / 8192.0f);
}

// ---------------------------------------------------------------------------
// staging helpers with hoisted addressing
// ---------------------------------------------------------------------------
DEVINL void stA(const u16* p, int uni, int lo, int ld, u16* dst, int w) {
    gload_lds16(p + uni + lo, dst + ((w << 3) << 6));
    gload_lds16(p + uni + lo + (ld << 7), dst + ((128 + (w << 3)) << 6));
}
DEVINL void stB(const u16* p, int uni, int lo, int ld, u16* dst, int w) {
    int d0 = ((w >> 2) << 6) + ((w & 3) << 3);
    gload_lds16(p + uni + lo, dst + (d0 << 6));
    gload_lds16(p + uni + lo + (ld << 7), dst + ((128 + d0) << 6));
}

// segment info for concatenated K (tiles 0-15: x/W_in, 16-47: h/W_hh)
struct SegU { const u16* pA; const u16* pB; int uA; int uB; int ld; int loA; int loB; };

DEVINL SegU segu(int kt, const u16* X, const u16* W1, const u16* H, const u16* W2,
                 int rbA, int rbB, int loA1, int loA2, int loB1, int loB2) {
    SegU s;
    if (kt < 16) {
        int k0 = kt << 6;
        s.pA = X; s.pB = W1; s.ld = 1024;
        s.uA = (rbA << 10) + k0; s.uB = (rbB << 10) + k0;
        s.loA = loA1; s.loB = loB1;
    } else {
        int k0 = (kt - 16) << 6;
        s.pA = H; s.pB = W2; s.ld = 2048;
        s.uA = (rbA << 11) + k0; s.uB = (rbB << 11) + k0;
        s.loA = loA2; s.loB = loB2;
    }
    return s;
}

#define STA(S, SET, BUF) stA((S).pA, (S).uA + ((SET) ? ((S).ld << 6) : 0), (S).loA, \
                             (S).ld, Alds + (BUF) * 16384 + (SET) * 4096, w)
#define STB(S, SET, BUF) stB((S).pB, (S).uB + ((SET) ? ((S).ld << 5) : 0), (S).loB, \
                             (S).ld, Blds + (BUF) * 16384 + (SET) * 2048, w)

// fragment reads: single VGPR base + compile-time byte imm
#define RD_A(MQ, BUF) do { \
    _Pragma("unroll") for (int i = 0; i < 4; ++i) { \
        afr[i][0] = *(const bf16x8*)(fA0 + (BUF) * 32768 + (MQ) * 8192 + i * 2048); \
        afr[i][1] = *(const bf16x8*)(fA1 + (BUF) * 32768 + (MQ) * 8192 + i * 2048); \
    } } while (0)

#define RD_B_ALL(BUF) do { \
    _Pragma("unroll") for (int n = 0; n < 4; ++n) { \
        bfr[n][0] = *(const bf16x8*)(fB0 + (BUF) * 32768 + n * 2048); \
        bfr[n][1] = *(const bf16x8*)(fB1 + (BUF) * 32768 + n * 2048); \
    } } while (0)

// 32 MFMA: one m-half x all n x both K-halves
#define MFMA_M(MQ) do { \
    _Pragma("unroll") for (int i = 0; i < 4; ++i) \
    _Pragma("unroll") for (int n = 0; n < 4; ++n) \
    _Pragma("unroll") for (int kk = 0; kk < 2; ++kk) \
        acc[(MQ)*4+i][n] = __builtin_amdgcn_mfma_f32_16x16x32_bf16( \
            afr[i][kk], bfr[n][kk], acc[(MQ)*4+i][n], 0, 0, 0); \
    } while (0)

// NO leading barrier: per-wave lgkm drain only -> waves slip within a phase.
#define PHASE_MID() do { \
    asm volatile("s_waitcnt lgkmcnt(0)" ::: "memory"); \
    __builtin_amdgcn_sched_barrier(0); \
    __builtin_amdgcn_s_setprio(1); \
    } while (0)

#define BAREND() do { \
    __builtin_amdgcn_s_setprio(0); \
    __builtin_amdgcn_sched_barrier(0); \
    asm volatile("s_barrier" ::: "memory"); \
    } while (0)

#define BAREND_VM() do { \
    __builtin_amdgcn_s_setprio(0); \
    __builtin_amdgcn_sched_barrier(0); \
    asm volatile("s_waitcnt vmcnt(4)" ::: "memory"); \
    asm volatile("s_barrier" ::: "memory"); \
    } while (0)

#define BAREND_VM3() do { \
    __builtin_amdgcn_s_setprio(0); \
    __builtin_amdgcn_sched_barrier(0); \
    asm volatile("s_waitcnt vmcnt(3)" ::: "memory"); \
    asm volatile("s_barrier" ::: "memory"); \
    } while (0)

// ---------------------------------------------------------------------------
// GEMM12, 256x256 tile, 8-wave, 2-phases-per-K-tile counted-vmcnt pipeline,
// single trailing barrier per phase. (frozen)
// ---------------------------------------------------------------------------
__global__ __launch_bounds__(512, 2) void gemm12_k8(
    const u16* __restrict__ Xbf, const u16* __restrict__ Win,
    const u16* __restrict__ Hbf, const u16* __restrict__ Whh,
    const float* __restrict__ bh,
    float* __restrict__ hnew_f32, u16* __restrict__ hnew_bf,
    float* __restrict__ act_out) {
    __shared__ alignas(16) u16 lds[4][16384];  // [A0|A1|B0|B1] = 128 KB
    u16* Alds = &lds[0][0];
    u16* Blds = &lds[2][0];
    int orig = blockIdx.x;
    int wg = (orig & 7) * 32 + (orig >> 3);    // XCD swizzle (256 % 8 == 0)
    int bm = wg >> 3, bn = wg & 7;
    int t = threadIdx.x, lane = t & 63, w = t >> 6;
    int wm = w >> 2, wn = w & 3;
    int l15 = lane & 15, hi = lane >> 4;
    int rbA = bm << 8, rbB = bn << 8;

    // invariant staging lane offsets
    int r0 = t >> 3, c8 = t & 7;
    int swz = (c8 ^ (r0 & 7)) << 3;
    int arB0 = ((r0 >> 5) << 6) + (r0 & 31);
    int loA1 = (r0 << 10) + swz, loA2 = (r0 << 11) + swz;
    int loB1 = (arB0 << 10) + swz, loB2 = (arB0 << 11) + swz;

    // fragment base pointers (swizzle term depends only on l15&7)
    int cb0 = (hi ^ (l15 & 7)) << 4;
    int cb1 = ((4 + hi) ^ (l15 & 7)) << 4;
    const char* fA0 = (const char*)(Alds + (((wm << 7) + l15) << 6)) + cb0;
    const char* fA1 = (const char*)(Alds + (((wm << 7) + l15) << 6)) + cb1;
    const char* fB0 = (const char*)(Blds + (((wn << 6) + l15) << 6)) + cb0;
    const char* fB1 = (const char*)(Blds + (((wn << 6) + l15) << 6)) + cb1;

    f32x4 acc[8][4];
#pragma unroll
    for (int i = 0; i < 8; ++i)
#pragma unroll
        for (int j = 0; j < 4; ++j) acc[i][j] = (f32x4){0.f, 0.f, 0.f, 0.f};
    bf16x8 afr[4][2], bfr[4][2];

    // prologue: tile0 all 4 sets + tile1 set0 (A,B) = 12 loads; wait to <=4
    {
        SegU s0 = segu(0, Xbf, Win, Hbf, Whh, rbA, rbB, loA1, loA2, loB1, loB2);
        SegU s1 = segu(1, Xbf, Win, Hbf, Whh, rbA, rbB, loA1, loA2, loB1, loB2);
        STA(s0, 0, 0); STB(s0, 0, 0);
        STA(s0, 1, 0); STB(s0, 1, 0);
        STA(s1, 0, 1); STB(s1, 0, 1);
    }
    asm volatile("s_waitcnt vmcnt(4)" ::: "memory");
    asm volatile("s_barrier" ::: "memory");

    for (int it = 0; it < 24; ++it) {
        int tb = it << 1;
        int t2 = tb + 2 < 47 ? tb + 2 : 47;
        int t3 = tb + 3 < 47 ? tb + 3 : 47;
        SegU s1 = segu(tb + 1, Xbf, Win, Hbf, Whh, rbA, rbB, loA1, loA2, loB1, loB2);
        SegU s2 = segu(t2,     Xbf, Win, Hbf, Whh, rbA, rbB, loA1, loA2, loB1, loB2);
        SegU s3 = segu(t3,     Xbf, Win, Hbf, Whh, rbA, rbB, loA1, loA2, loB1, loB2);

        // phase A: tile tb (buf0), m0; stage (tb+1,set1)->buf1
        RD_B_ALL(0); RD_A(0, 0);
        STA(s1, 1, 1); STB(s1, 1, 1);
        PHASE_MID(); MFMA_M(0); BAREND();
        // phase B: tile tb, m1; stage (tb+2,set0)->buf0
        RD_A(1, 0);
        STA(s2, 0, 0); STB(s2, 0, 0);
        PHASE_MID(); MFMA_M(1); BAREND_VM();
        // phase C: tile tb+1 (buf1), m0; stage (tb+2,set1)->buf0
        RD_B_ALL(1); RD_A(0, 1);
        STA(s2, 1, 0); STB(s2, 1, 0);
        PHASE_MID(); MFMA_M(0); BAREND();
        // phase D: tile tb+1, m1; stage (tb+3,set0)->buf1
        RD_A(1, 1);
        STA(s3, 0, 1); STB(s3, 0, 1);
        PHASE_MID(); MFMA_M(1); BAREND_VM();
    }

    // epilogue: bias + relu + stores + act column sums
    const int row0 = (bm << 8) + (wm << 7);
    const int col0 = (bn << 8) + (wn << 6);
#pragma unroll
    for (int n = 0; n < 4; ++n) {
        int col = col0 + (n << 4) + l15;
        float bhv = bh[col];
        float csum = 0.f;
#pragma unroll
        for (int m = 0; m < 8; ++m) {
#pragma unroll
            for (int r = 0; r < 4; ++r) {
                int row = row0 + (m << 4) + (hi << 2) + r;
                float v = fmaxf(acc[m][n][r] + bhv, 0.f);
                size_t off = (size_t)row * 2048 + col;
                hnew_f32[off] = v;
                hnew_bf[off] = f2bf(v);
                csum += v;
            }
        }
        csum += __shfl_xor(csum, 16, 64);
        csum += __shfl_xor(csum, 32, 64);
        if (lane < 16) atomicAdd(&act_out[col], csum * (1.0f / 8192.0f));
    }
}

// ---------------------------------------------------------------------------
// GEMM3: y = h_new@W_out.T + b_out (frozen)
// ---------------------------------------------------------------------------
#define G3_STA(KT, SET, BUF) do { \
    int uni_ = uA + ((KT) << 6) + ((SET) ? (2048 << 6) : 0); \
    u16* dst_ = g3A + (BUF) * 16384 + (SET) * 4096; \
    gload_lds16(Hn + uni_ + lo, dst_ + ((w << 3) << 6)); \
    gload_lds16(Hn + uni_ + lo + (2048 << 7), dst_ + ((128 + (w << 3)) << 6)); \
    } while (0)

#define G3_STB(KT, SET, BUF) do { \
    int uni_ = uB + ((KT) << 6) + ((SET) ? (2048 << 6) : 0); \
    gload_lds16(Wout + uni_ + lo, g3B + (BUF) * 8192 + (SET) * 4096 + ((w << 3) << 6)); \
    } while (0)

#define G3_RD_A(MQ, BUF) do { \
    _Pragma("unroll") for (int i = 0; i < 4; ++i) { \
        afr[i][0] = *(const bf16x8*)(fA0 + (BUF) * 32768 + (MQ) * 8192 + i * 2048); \
        afr[i][1] = *(const bf16x8*)(fA1 + (BUF) * 32768 + (MQ) * 8192 + i * 2048); \
    } } while (0)

#define G3_RD_B(BUF) do { \
    _Pragma("unroll") for (int n = 0; n < 2; ++n) { \
        bfr[n][0] = *(const bf16x8*)(fB0 + (BUF) * 16384 + n * 2048); \
        bfr[n][1] = *(const bf16x8*)(fB1 + (BUF) * 16384 + n * 2048); \
    } } while (0)

#define G3_MFMA(MQ) do { \
    _Pragma("unroll") for (int i = 0; i < 4; ++i) \
    _Pragma("unroll") for (int n = 0; n < 2; ++n) \
    _Pragma("unroll") for (int kk = 0; kk < 2; ++kk) \
        acc[(MQ)*4+i][n] = __builtin_amdgcn_mfma_f32_16x16x32_bf16( \
            afr[i][kk], bfr[n][kk], acc[(MQ)*4+i][n], 0, 0, 0); \
    } while (0)

__global__ __launch_bounds__(512, 1) void gemm3_k8(
    const u16* __restrict__ Hn, const u16* __restrict__ Wout,
    const float* __restrict__ bout, float* __restrict__ y) {
    __shared__ alignas(16) u16 lds[49152];  // A: 2x16384, B: 2x8192 = 96 KB
    u16* g3A = &lds[0];
    u16* g3B = &lds[32768];
    int orig = blockIdx.x;
    int wg = (orig & 7) * 32 + (orig >> 3);   // XCD swizzle (256 % 8 == 0)
    int bm = wg >> 3, bn = wg & 7;            // 32 x 8
    int t = threadIdx.x, lane = t & 63, w = t >> 6;
    int wm = w >> 2, wn = w & 3;
    int l15 = lane & 15, hi = lane >> 4;

    // staging lane offsets (both operands lda=2048)
    int r0 = t >> 3, c8 = t & 7;
    int swz = (c8 ^ (r0 & 7)) << 3;
    int lo = (r0 << 11) + swz;
    int uA = (bm << 8) << 11;   // bm*256*2048
    int uB = (bn << 7) << 11;   // bn*128*2048

    // fragment bases
    int cb0 = (hi ^ (l15 & 7)) << 4;
    int cb1 = ((4 + hi) ^ (l15 & 7)) << 4;
    const char* fA0 = (const char*)(g3A + (((wm << 7) + l15) << 6)) + cb0;
    const char* fA1 = (const char*)(g3A + (((wm << 7) + l15) << 6)) + cb1;
    const char* fB0 = (const char*)(g3B + (((wn << 5) + l15) << 6)) + cb0;
    const char* fB1 = (const char*)(g3B + (((wn << 5) + l15) << 6)) + cb1;

    f32x4 acc[8][2];
#pragma unroll
    for (int i = 0; i < 8; ++i)
#pragma unroll
        for (int j = 0; j < 2; ++j) acc[i][j] = (f32x4){0.f, 0.f, 0.f, 0.f};
    bf16x8 afr[4][2], bfr[2][2];

    // prologue: tile0 full (6 loads) + tile1 set0 (3 loads); wait to <=3
    G3_STA(0, 0, 0); G3_STB(0, 0, 0);
    G3_STA(0, 1, 0); G3_STB(0, 1, 0);
    G3_STA(1, 0, 1); G3_STB(1, 0, 1);
    asm volatile("s_waitcnt vmcnt(3)" ::: "memory");
    asm volatile("s_barrier" ::: "memory");

    for (int it = 0; it < 16; ++it) {
        int tb = it << 1;
        int t2 = tb + 2 < 31 ? tb + 2 : 31;
        int t3 = tb + 3 < 31 ? tb + 3 : 31;
        int t1 = tb + 1;

        // phase A: tile tb (buf0), m0; stage (tb+1,set1)->buf1
        G3_RD_B(0); G3_RD_A(0, 0);
        G3_STA(t1, 1, 1); G3_STB(t1, 1, 1);
        PHASE_MID(); G3_MFMA(0); BAREND();
        // phase B: tile tb, m1; stage (tb+2,set0)->buf0
        G3_RD_A(1, 0);
        G3_STA(t2, 0, 0); G3_STB(t2, 0, 0);
        PHASE_MID(); G3_MFMA(1); BAREND_VM3();
        // phase C: tile tb+1 (buf1), m0; stage (tb+2,set1)->buf0
        G3_RD_B(1); G3_RD_A(0, 1);
        G3_STA(t2, 1, 0); G3_STB(t2, 1, 0);
        PHASE_MID(); G3_MFMA(0); BAREND();
        // phase D: tile tb+1, m1; stage (tb+3,set0)->buf1
        G3_RD_A(1, 1);
        G3_STA(t3, 0, 1); G3_STB(t3, 0, 1);
        PHASE_MID(); G3_MFMA(1); BAREND_VM3();
    }

    const int row0 = (bm << 8) + (wm << 7);
    const int col0 = (bn << 7) + (wn << 5);
#pragma unroll
    for (int n = 0; n < 2; ++n) {
        int col = col0 + (n << 4) + l15;
        float bv = bout[col];
#pragma unroll
        for (int m = 0; m < 8; ++m) {
#pragma unroll
            for (int r = 0; r < 4; ++r) {
                int row = row0 + (m << 4) + (hi << 2) + r;
                y[(size_t)row * 1024 + col] = acc[m][n][r] + bv;
            }
        }
    }
}

// ---------------------------------------------------------------------------
extern "C" void kernel_launch(void* const* d_in, const int* in_sizes, int n_in,
                              void* d_out, int out_size, void* d_ws, size_t ws_size,
                              hipStream_t stream) {
    const float* x     = (const float*)d_in[0];
    const float* h     = (const float*)d_in[1];
    const float* W_in  = (const float*)d_in[2];
    const float* W_hh  = (const float*)d_in[3];
    const float* b_h   = (const float*)d_in[4];
    const float* W_out = (const float*)d_in[5];
    const float* b_out = (const float*)d_in[6];

    float* out  = (float*)d_out;
    float* y    = out;
    float* hnew = out + 8388608;
    float* act  = out + 8388608 + 16777216;
    float* rec  = act + 2048;

    char* ws = (char*)d_ws;
    u16* x_bf    = (u16*)(ws);
    u16* h_bf    = (u16*)(ws + (16ull << 20));
    u16* win_bf  = (u16*)(ws + (48ull << 20));
    u16* whh_bf  = (u16*)(ws + (52ull << 20));
    u16* wout_bf = (u16*)(ws + (60ull << 20));
    u16* hn_bf   = (u16*)(ws + (64ull << 20));
    float* partial = (float*)(ws + (96ull << 20));  // 256 x 2048 f32 = 2 MB

    // act accumulated via atomics in gemm12 -> zero it each call
    hipMemsetAsync(act, 0, 2048 * sizeof(float), stream);

    cvt_all_kernel<<<8448, 256, 0, stream>>>(x, x_bf, W_in, win_bf, W_hh, whh_bf,
                                             W_out, wout_bf, h, h_bf, partial);
    rec_reduce_kernel<<<32, 256, 0, stream>>>(partial, rec);

    gemm12_k8<<<256, 512, 0, stream>>>(x_bf, win_bf, h_bf, whh_bf, b_h,
                                       hnew, hn_bf, act);
    gemm3_k8<<<256, 512, 0, stream>>>(hn_bf, wout_bf, b_out, y);
}